// Round 4
// baseline (286.246 us; speedup 1.0000x reference)
//
#include <hip/hip_runtime.h>

#define N_NODES 50000
#define E_EDGES 800000
#define IN_DIM 256
#define HID 128
#define OUT_DIM 64
#define SLOT 64   // per-node srcidx bucket; P(deg>64)~1e-19 for Poisson(16), clamped

#define LR 64
#define AP 264    // As row stride (256 + 8 pad u16) -> 528B = 132 dw = 4 mod 32: 2-way, free
#define NBUILD ((E_EDGES / 8 + 255) / 256)      // 391
#define NLIN ((N_NODES + LR - 1) / LR)          // 782

typedef unsigned short u16;
typedef __attribute__((ext_vector_type(8))) short short8;
typedef __attribute__((ext_vector_type(4))) float floatx4;

__device__ __forceinline__ u16 f2bf(float f) {
    unsigned u = __float_as_uint(f);
    unsigned r = (u + 0x7FFFu + ((u >> 16) & 1u)) >> 16;  // RNE
    return (u16)r;
}
__device__ __forceinline__ void bf8_unpack(uint4 v, float* f) {
    f[0] = __uint_as_float(v.x << 16); f[1] = __uint_as_float(v.x & 0xffff0000u);
    f[2] = __uint_as_float(v.y << 16); f[3] = __uint_as_float(v.y & 0xffff0000u);
    f[4] = __uint_as_float(v.z << 16); f[5] = __uint_as_float(v.z & 0xffff0000u);
    f[6] = __uint_as_float(v.w << 16); f[7] = __uint_as_float(v.w & 0xffff0000u);
}
__device__ __forceinline__ uint4 bf8_pack(const float* f) {
    uint4 o;
    o.x = f2bf(f[0]) | ((unsigned)f2bf(f[1]) << 16);
    o.y = f2bf(f[2]) | ((unsigned)f2bf(f[3]) << 16);
    o.z = f2bf(f[4]) | ((unsigned)f2bf(f[5]) << 16);
    o.w = f2bf(f[6]) | ((unsigned)f2bf(f[7]) << 16);
    return o;
}

// ---------- k_pre: zero cnt + one-time weight transposes to bf16 ----------
// W0T/Wct built ONCE (not per lin block; the x782 reconversion was r1/r2's
// wasted VALU). Replaces hipMemsetAsync(cnt).
__global__ __launch_bounds__(256) void k_pre(const float* __restrict__ W0,
                                             const float* __restrict__ Wc,
                                             u16* __restrict__ W0T,
                                             u16* __restrict__ Wct,
                                             int* __restrict__ cnt) {
    const int gid = blockIdx.x * 256 + threadIdx.x;
    if (gid < N_NODES / 4) ((int4*)cnt)[gid] = (int4){0, 0, 0, 0};
    if (gid < IN_DIM * HID) {      // W0T[n*256+k] = bf16(W0[k][n])
        const int n = gid >> 8, k = gid & (IN_DIM - 1);
        W0T[gid] = f2bf(W0[k * HID + n]);
    }
    if (gid < HID * OUT_DIM) {     // Wct[o*128+k] = bf16(Wc[k][o])
        const int o = gid >> 7, k = gid & (HID - 1);
        Wct[gid] = f2bf(Wc[k * OUT_DIM + o]);
    }
}

// ---------- FUSED front: slot-CSR build (blocks [0,391)) + h0 GEMM
// (blocks [391,1173)).
// r3 post-mortem: LDS-free lin LOST 7us — per-lane serialized K-chain at
// VGPR=60 killed MLP (all pipes idler, duration longer). r4: stage the WHOLE
// 64x256 x-tile in LDS with fully-coalesced cooperative loads (16 indep
// float4/thread), ONE barrier, then barrier-free MFMA streaming B from
// L2-hot W0T. Keeps r3's conversion savings + r1's staging MLP, drops r1's
// per-K-step double barrier.
__global__ __launch_bounds__(256) void k_front(
    const float* __restrict__ x, const u16* __restrict__ W0T,
    const float* __restrict__ b0, const float* __restrict__ aw1,
    u16* __restrict__ h, float* __restrict__ sa, float* __restrict__ sb,
    const int* __restrict__ ei, int* __restrict__ cnt,
    u16* __restrict__ srcidx) {
    __shared__ u16 As[LR][AP];   // 33792 B -> 4 blocks/CU
    if (blockIdx.x < NBUILD) {
        // ----- build path: 8 edges/thread (r10: 8/thr=45us; r11: 2/thr=59us)
        const int gid = blockIdx.x * 256 + threadIdx.x;
        if (gid >= E_EDGES / 8) return;
        const int4 w0 = ((const int4*)ei)[2 * gid];
        const int4 w1 = ((const int4*)ei)[2 * gid + 1];
        const int4 c0 = ((const int4*)(ei + E_EDGES))[2 * gid];
        const int4 c1 = ((const int4*)(ei + E_EDGES))[2 * gid + 1];
        const int p0 = atomicAdd(&cnt[c0.x], 1);
        const int p1 = atomicAdd(&cnt[c0.y], 1);
        const int p2 = atomicAdd(&cnt[c0.z], 1);
        const int p3 = atomicAdd(&cnt[c0.w], 1);
        const int p4 = atomicAdd(&cnt[c1.x], 1);
        const int p5 = atomicAdd(&cnt[c1.y], 1);
        const int p6 = atomicAdd(&cnt[c1.z], 1);
        const int p7 = atomicAdd(&cnt[c1.w], 1);
        if (p0 < SLOT) srcidx[(c0.x << 6) + p0] = (u16)w0.x;
        if (p1 < SLOT) srcidx[(c0.y << 6) + p1] = (u16)w0.y;
        if (p2 < SLOT) srcidx[(c0.z << 6) + p2] = (u16)w0.z;
        if (p3 < SLOT) srcidx[(c0.w << 6) + p3] = (u16)w0.w;
        if (p4 < SLOT) srcidx[(c1.x << 6) + p4] = (u16)w1.x;
        if (p5 < SLOT) srcidx[(c1.y << 6) + p5] = (u16)w1.y;
        if (p6 < SLOT) srcidx[(c1.z << 6) + p6] = (u16)w1.z;
        if (p7 < SLOT) srcidx[(c1.w << 6) + p7] = (u16)w1.w;
        return;
    }

    // ----- lin path: h0 = relu(x@W0+b0) via MFMA + fused layer-1 scores
    const int t = threadIdx.x;
    const int lane = t & 63;
    const int w = t >> 6;
    const int sub = lane & 15;
    const int quad = lane >> 4;
    const int row0 = (blockIdx.x - NBUILD) * LR;

    // stage x tile: iter j loads 4KB contiguous (256 thr x float4), rows 4j..4j+3
    {
        const int rsub = t >> 6;        // 0..3
        const int c4 = (t & 63) * 4;    // float col 0..252
        #pragma unroll
        for (int j = 0; j < 16; ++j) {
            const int r = 4 * j + rsub;
            int gr = row0 + r;
            if (gr > N_NODES - 1) gr = N_NODES - 1;
            const float4 f = *(const float4*)(x + (size_t)gr * IN_DIM + c4);
            uint2 p;
            p.x = f2bf(f.x) | ((unsigned)f2bf(f.y) << 16);
            p.y = f2bf(f.z) | ((unsigned)f2bf(f.w) << 16);
            *(uint2*)&As[r][c4] = p;
        }
    }
    __syncthreads();   // the ONLY barrier; compute phase is barrier-free

    floatx4 acc[8];
    #pragma unroll
    for (int i = 0; i < 8; ++i) acc[i] = (floatx4){0.f, 0.f, 0.f, 0.f};

    const u16* wbase = W0T + (size_t)sub * IN_DIM + quad * 8;
    #pragma unroll
    for (int ks = 0; ks < IN_DIM; ks += 32) {
        const short8 a = *(const short8*)&As[w * 16 + sub][ks + quad * 8];
        #pragma unroll
        for (int ct = 0; ct < 8; ++ct) {
            const short8 bb = *(const short8*)(wbase + ct * 16 * IN_DIM + ks);
            acc[ct] = __builtin_amdgcn_mfma_f32_16x16x32_bf16(a, bb, acc[ct], 0, 0, 0);
        }
    }

    // epilogue: bias + relu + bf16 store; fused layer-1 scores
    float bias[8], w1c[8], w2c[8];
    #pragma unroll
    for (int ct = 0; ct < 8; ++ct) {
        const int col = ct * 16 + sub;
        bias[ct] = b0[col];
        w1c[ct] = aw1[col];
        w2c[ct] = aw1[HID + col];
    }
    #pragma unroll
    for (int reg = 0; reg < 4; ++reg) {
        const int gr = row0 + w * 16 + quad * 4 + reg;
        const bool ok = gr < N_NODES;
        float ps = 0.f, pd = 0.f;
        #pragma unroll
        for (int ct = 0; ct < 8; ++ct) {
            const float val = fmaxf(acc[ct][reg] + bias[ct], 0.f);
            if (ok) h[(size_t)gr * HID + ct * 16 + sub] = f2bf(val);
            ps += val * w1c[ct];
            pd += val * w2c[ct];
        }
        #pragma unroll
        for (int off = 1; off < 16; off <<= 1) {
            ps += __shfl_xor(ps, off);
            pd += __shfl_xor(pd, off);
        }
        if (sub == 0 && ok) { sa[gr] = ps; sb[gr] = pd; }
    }
}

// ---------- slot-CSR aggregation + eps-mix + relu + next-layer scores ----
// One QUARTER-WAVE (16 lanes) per node; lane sub owns channels 8*sub..8*sub+7.
// No LDS, no block barrier — waves retire independently (r12: coupling waves
// cost +44us; r2: shuffle-GEMM epilogue fusion cost ~6us — do not re-add).
// r4: 16-edge batches (v[16] in flight, 2x the gather MLP of the 8-batch
// version); distributed tanh now uses all 16 lanes (s[sub]).
__global__ __launch_bounds__(256) void k_agg(const u16* __restrict__ hin,
                                             const float* __restrict__ sa,
                                             const float* __restrict__ sb,
                                             const float* __restrict__ attb,
                                             const float* __restrict__ epsp,
                                             const int* __restrict__ cnt,
                                             const u16* __restrict__ srcidx,
                                             u16* __restrict__ hout,
                                             const float* __restrict__ attw_next,
                                             float* __restrict__ sa_next,
                                             float* __restrict__ sb_next) {
    const int qid = threadIdx.x >> 4;   // 16 quarter-waves per block
    const int sub = threadIdx.x & 15;
    const int n = blockIdx.x * 16 + qid;
    if (n >= N_NODES) return;
    const float b = attb[0];
    const float sbn = sb[n];
    const int beg = n << 6;
    int deg = cnt[n];
    if (deg > SLOT) deg = SLOT;
    const int end = beg + deg;
    // issue the self-row load early; consumed only in the epilogue
    const uint4 svself = *(const uint4*)(hin + (size_t)n * HID + sub * 8);
    float acc[8];
    #pragma unroll
    for (int j = 0; j < 8; ++j) acc[j] = 0.f;

    int e = beg;
    for (; e + 16 <= end; e += 16) {
        const uint4 i0 = *(const uint4*)(srcidx + e);
        const uint4 i1 = *(const uint4*)(srcidx + e + 8);
        int s[16];
        s[0]  = (int)(i0.x & 0xffffu); s[1]  = (int)(i0.x >> 16);
        s[2]  = (int)(i0.y & 0xffffu); s[3]  = (int)(i0.y >> 16);
        s[4]  = (int)(i0.z & 0xffffu); s[5]  = (int)(i0.z >> 16);
        s[6]  = (int)(i0.w & 0xffffu); s[7]  = (int)(i0.w >> 16);
        s[8]  = (int)(i1.x & 0xffffu); s[9]  = (int)(i1.x >> 16);
        s[10] = (int)(i1.y & 0xffffu); s[11] = (int)(i1.y >> 16);
        s[12] = (int)(i1.z & 0xffffu); s[13] = (int)(i1.z >> 16);
        s[14] = (int)(i1.w & 0xffffu); s[15] = (int)(i1.w >> 16);
        uint4 v[16];
        #pragma unroll
        for (int i = 0; i < 16; ++i)
            v[i] = *(const uint4*)(hin + (size_t)s[i] * HID + sub * 8);
        // one tanh per lane serves all 16 edges (lane sub owns edge sub)
        const float tt = tanhf(sa[s[sub]] + sbn + b);
        float al[16];
        #pragma unroll
        for (int i = 0; i < 16; ++i) al[i] = __shfl(tt, i, 16);
        #pragma unroll
        for (int i = 0; i < 16; ++i) {
            float f[8];
            bf8_unpack(v[i], f);
            #pragma unroll
            for (int j = 0; j < 8; ++j) acc[j] += al[i] * f[j];
        }
    }
    const int rem = end - e;   // 0..15
    if (rem > 0) {
        // slot is 64-deep so reading 16 entries here is always in-bounds;
        // entries >= rem are stale garbage — never dereferenced (guarded).
        const uint4 i0 = *(const uint4*)(srcidx + e);
        const uint4 i1 = *(const uint4*)(srcidx + e + 8);
        int s[16];
        s[0]  = (int)(i0.x & 0xffffu); s[1]  = (int)(i0.x >> 16);
        s[2]  = (int)(i0.y & 0xffffu); s[3]  = (int)(i0.y >> 16);
        s[4]  = (int)(i0.z & 0xffffu); s[5]  = (int)(i0.z >> 16);
        s[6]  = (int)(i0.w & 0xffffu); s[7]  = (int)(i0.w >> 16);
        s[8]  = (int)(i1.x & 0xffffu); s[9]  = (int)(i1.x >> 16);
        s[10] = (int)(i1.y & 0xffffu); s[11] = (int)(i1.y >> 16);
        s[12] = (int)(i1.z & 0xffffu); s[13] = (int)(i1.z >> 16);
        s[14] = (int)(i1.w & 0xffffu); s[15] = (int)(i1.w >> 16);
        const float tt = (sub < rem) ? tanhf(sa[s[sub]] + sbn + b) : 0.f;
        float al[16];
        #pragma unroll
        for (int i = 0; i < 16; ++i) al[i] = __shfl(tt, i, 16);
        #pragma unroll
        for (int i = 0; i < 16; ++i) {
            if (i < rem) {
                const uint4 v = *(const uint4*)(hin + (size_t)s[i] * HID + sub * 8);
                float f[8];
                bf8_unpack(v, f);
                #pragma unroll
                for (int j = 0; j < 8; ++j) acc[j] += al[i] * f[j];
            }
        }
    }

    const float eps = epsp[0];
    const float om = 1.f - eps;
    float self[8], hv[8];
    bf8_unpack(svself, self);
    #pragma unroll
    for (int j = 0; j < 8; ++j)
        hv[j] = fmaxf(eps * self[j] + om * acc[j], 0.f);
    *(uint4*)(hout + (size_t)n * HID + sub * 8) = bf8_pack(hv);

    if (attw_next != nullptr) {
        float psum = 0.f, dsum = 0.f;
        #pragma unroll
        for (int j = 0; j < 8; ++j) {
            psum += hv[j] * attw_next[sub * 8 + j];
            dsum += hv[j] * attw_next[HID + sub * 8 + j];
        }
        #pragma unroll
        for (int off = 1; off < 16; off <<= 1) {
            psum += __shfl_xor(psum, off);
            dsum += __shfl_xor(dsum, off);
        }
        if (sub == 0) { sa_next[n] = psum; sb_next[n] = dsum; }
    }
}

// ---------- out = h2 @ Wc + bc via MFMA; LDS-free, barrier-free ----------
// A-frags: 16B contiguous bf16 reads straight from L3-hot h (just written);
// B-frags from L2-hot Wct. 16 MFMAs total per wave; latency-tolerant.
__global__ __launch_bounds__(256) void k_out_mfma(const u16* __restrict__ h,
                                                  const u16* __restrict__ Wct,
                                                  const float* __restrict__ bc,
                                                  float* __restrict__ out) {
    const int t = threadIdx.x;
    const int lane = t & 63;
    const int w = t >> 6;
    const int sub = lane & 15;
    const int quad = lane >> 4;
    const int row0 = blockIdx.x * LR;

    int gr_a = row0 + w * 16 + sub;
    if (gr_a > N_NODES - 1) gr_a = N_NODES - 1;
    const u16* hrow = h + (size_t)gr_a * HID + quad * 8;
    const u16* wbase = Wct + (size_t)sub * HID + quad * 8;

    floatx4 acc[4];
    #pragma unroll
    for (int j = 0; j < 4; ++j) acc[j] = (floatx4){0.f, 0.f, 0.f, 0.f};

    #pragma unroll
    for (int ks = 0; ks < HID; ks += 32) {
        const short8 a = *(const short8*)(hrow + ks);
        #pragma unroll
        for (int ct = 0; ct < 4; ++ct) {
            const short8 bb = *(const short8*)(wbase + ct * 16 * HID + ks);
            acc[ct] = __builtin_amdgcn_mfma_f32_16x16x32_bf16(a, bb, acc[ct], 0, 0, 0);
        }
    }

    #pragma unroll
    for (int ct = 0; ct < 4; ++ct) {
        const float bias = bc[ct * 16 + sub];
        #pragma unroll
        for (int reg = 0; reg < 4; ++reg) {
            const int gr = row0 + w * 16 + quad * 4 + reg;
            if (gr < N_NODES)
                out[(size_t)gr * OUT_DIM + ct * 16 + sub] = acc[ct][reg] + bias;
        }
    }
}

extern "C" void kernel_launch(void* const* d_in, const int* in_sizes, int n_in,
                              void* d_out, int out_size, void* d_ws, size_t ws_size,
                              hipStream_t stream) {
    const float* x   = (const float*)d_in[0];
    const int*   ei  = (const int*)d_in[1];
    const float* W0  = (const float*)d_in[2];
    const float* b0  = (const float*)d_in[3];
    const float* aw1 = (const float*)d_in[4];
    const float* ab1 = (const float*)d_in[5];
    const float* e1  = (const float*)d_in[6];
    const float* aw2 = (const float*)d_in[7];
    const float* ab2 = (const float*)d_in[8];
    const float* e2  = (const float*)d_in[9];
    const float* Wc  = (const float*)d_in[10];
    const float* bc  = (const float*)d_in[11];
    float* out = (float*)d_out;

    // workspace layout
    u16* hA  = (u16*)d_ws;                             // N*HID bf16
    u16* hB  = hA + (size_t)N_NODES * HID;             // N*HID bf16
    u16* W0T = hB + (size_t)N_NODES * HID;             // 256*128 bf16 (64 KB)
    u16* Wct = W0T + IN_DIM * HID;                     // 64*128 bf16 (16 KB)
    float* sa1 = (float*)(Wct + HID * OUT_DIM);        // N
    float* sb1 = sa1 + N_NODES;
    float* sa2 = sb1 + N_NODES;
    float* sb2 = sa2 + N_NODES;
    int* cnt    = (int*)(sb2 + N_NODES);               // N
    u16* srcidx = (u16*)(cnt + N_NODES);               // N*SLOT u16 (6.4 MB)

    k_pre<<<128, 256, 0, stream>>>(W0, Wc, W0T, Wct, cnt);
    k_front<<<NBUILD + NLIN, 256, 0, stream>>>(x, W0T, b0, aw1, hA, sa1, sb1,
                                               ei, cnt, srcidx);
    k_agg<<<(N_NODES + 15) / 16, 256, 0, stream>>>(hA, sa1, sb1, ab1, e1, cnt, srcidx,
                                                   hB, aw2, sa2, sb2);
    k_agg<<<(N_NODES + 15) / 16, 256, 0, stream>>>(hB, sa2, sb2, ab2, e2, cnt, srcidx,
                                                   hA, nullptr, nullptr, nullptr);
    k_out_mfma<<<NLIN, 256, 0, stream>>>(hA, Wct, bc, out);
}

// Round 5
// 239.280 us; speedup vs baseline: 1.1963x; 1.1963x over previous
//
#include <hip/hip_runtime.h>

#define N_NODES 50000
#define E_EDGES 800000
#define IN_DIM 256
#define HID 128
#define OUT_DIM 64
#define SLOT 64   // per-node srcidx bucket; P(deg>64)~1e-19 for Poisson(16), clamped

#define LR 64
#define KS 64
#define KP 72   // 64 + 8 pad (u16)
#define HP 136  // 128 + 8 pad (u16)

#define NBUILD ((E_EDGES / 8 + 255) / 256)      // 391
#define NLIN ((N_NODES + LR - 1) / LR)          // 782

// Journal (do not retry):
//  r2: fusing out-GEMM into agg2 via shfl+LDS epilogue: -1 dispatch but +6us
//      (128 serial shfl/ds_read steps per node) -> keep k_out on MFMA.
//  r3: LDS-free lin (per-lane global B+A chains): 80us, MLP collapse at VGPR=60.
//  r4: single-barrier lin, B from global W0T: 82us (same mechanism as r3);
//      16-edge agg batches: VGPR blowup, occupancy crash, ~+25us/dispatch.
//  => lin structure pinned to r1: cooperative LDS stage of A AND B per K-step.

typedef unsigned short u16;
typedef __attribute__((ext_vector_type(8))) short short8;
typedef __attribute__((ext_vector_type(4))) float floatx4;

__device__ __forceinline__ u16 f2bf(float f) {
    unsigned u = __float_as_uint(f);
    unsigned r = (u + 0x7FFFu + ((u >> 16) & 1u)) >> 16;  // RNE
    return (u16)r;
}
__device__ __forceinline__ void bf8_unpack(uint4 v, float* f) {
    f[0] = __uint_as_float(v.x << 16); f[1] = __uint_as_float(v.x & 0xffff0000u);
    f[2] = __uint_as_float(v.y << 16); f[3] = __uint_as_float(v.y & 0xffff0000u);
    f[4] = __uint_as_float(v.z << 16); f[5] = __uint_as_float(v.z & 0xffff0000u);
    f[6] = __uint_as_float(v.w << 16); f[7] = __uint_as_float(v.w & 0xffff0000u);
}
__device__ __forceinline__ uint4 bf8_pack(const float* f) {
    uint4 o;
    o.x = f2bf(f[0]) | ((unsigned)f2bf(f[1]) << 16);
    o.y = f2bf(f[2]) | ((unsigned)f2bf(f[3]) << 16);
    o.z = f2bf(f[4]) | ((unsigned)f2bf(f[5]) << 16);
    o.w = f2bf(f[6]) | ((unsigned)f2bf(f[7]) << 16);
    return o;
}

// ---------- k_pre: zero cnt + ONE-TIME weight transposes to bf16 ----------
// Replaces hipMemsetAsync(cnt) (same dispatch count). W0T/Wct built once
// instead of per lin block (r1 re-did 32 strided f32 loads + 32 f2bf per
// thread per K-iter x782 blocks).
__global__ __launch_bounds__(256) void k_pre(const float* __restrict__ W0,
                                             const float* __restrict__ Wc,
                                             u16* __restrict__ W0T,
                                             u16* __restrict__ Wct,
                                             int* __restrict__ cnt) {
    const int gid = blockIdx.x * 256 + threadIdx.x;
    if (gid < N_NODES / 4) ((int4*)cnt)[gid] = (int4){0, 0, 0, 0};
    if (gid < IN_DIM * HID) {      // W0T[n*256+k] = bf16(W0[k][n])
        const int n = gid >> 8, k = gid & (IN_DIM - 1);
        W0T[gid] = f2bf(W0[k * HID + n]);
    }
    if (gid < HID * OUT_DIM) {     // Wct[o*128+k] = bf16(Wc[k][o])
        const int o = gid >> 7, k = gid & (HID - 1);
        Wct[gid] = f2bf(Wc[k * OUT_DIM + o]);
    }
}

// ---------- FUSED front: slot-CSR build (blocks [0,391)) + h0 MFMA GEMM
// (blocks [391,1173)). Structure = r1 (best measured, 71us): cooperative
// LDS staging of A and B per K-step, 2 barriers/K-step. Only delta vs r1:
// B-stage copies bf16 from pre-transposed W0T (4 coalesced uint4/thread)
// instead of 32 strided f32 loads + f2bf.
__global__ __launch_bounds__(256) void k_front(
    const float* __restrict__ x, const u16* __restrict__ W0T,
    const float* __restrict__ b0, const float* __restrict__ aw1,
    u16* __restrict__ h, float* __restrict__ sa, float* __restrict__ sb,
    const int* __restrict__ ei, int* __restrict__ cnt,
    u16* __restrict__ srcidx) {
    __shared__ u16 As[LR][KP];    // 9.2 KB
    __shared__ u16 Bs[HID][KP];   // 18.4 KB

    if (blockIdx.x < NBUILD) {
        // ----- build path: 8 edges/thread (r10: 8/thr=45us; r11: 2/thr=59us)
        const int gid = blockIdx.x * 256 + threadIdx.x;
        if (gid >= E_EDGES / 8) return;
        const int4 w0 = ((const int4*)ei)[2 * gid];
        const int4 w1 = ((const int4*)ei)[2 * gid + 1];
        const int4 c0 = ((const int4*)(ei + E_EDGES))[2 * gid];
        const int4 c1 = ((const int4*)(ei + E_EDGES))[2 * gid + 1];
        const int p0 = atomicAdd(&cnt[c0.x], 1);
        const int p1 = atomicAdd(&cnt[c0.y], 1);
        const int p2 = atomicAdd(&cnt[c0.z], 1);
        const int p3 = atomicAdd(&cnt[c0.w], 1);
        const int p4 = atomicAdd(&cnt[c1.x], 1);
        const int p5 = atomicAdd(&cnt[c1.y], 1);
        const int p6 = atomicAdd(&cnt[c1.z], 1);
        const int p7 = atomicAdd(&cnt[c1.w], 1);
        if (p0 < SLOT) srcidx[(c0.x << 6) + p0] = (u16)w0.x;
        if (p1 < SLOT) srcidx[(c0.y << 6) + p1] = (u16)w0.y;
        if (p2 < SLOT) srcidx[(c0.z << 6) + p2] = (u16)w0.z;
        if (p3 < SLOT) srcidx[(c0.w << 6) + p3] = (u16)w0.w;
        if (p4 < SLOT) srcidx[(c1.x << 6) + p4] = (u16)w1.x;
        if (p5 < SLOT) srcidx[(c1.y << 6) + p5] = (u16)w1.y;
        if (p6 < SLOT) srcidx[(c1.z << 6) + p6] = (u16)w1.z;
        if (p7 < SLOT) srcidx[(c1.w << 6) + p7] = (u16)w1.w;
        return;
    }

    // ----- lin path: h0 = relu(x@W0+b0) via MFMA + fused layer-1 scores
    const int t = threadIdx.x;
    const int lane = t & 63;
    const int w = t >> 6;
    const int sub = lane & 15;
    const int quad = lane >> 4;
    const int row0 = (blockIdx.x - NBUILD) * LR;

    floatx4 acc[8];
    #pragma unroll
    for (int i = 0; i < 8; ++i) acc[i] = (floatx4){0.f, 0.f, 0.f, 0.f};

    const int ar = t >> 2;          // A-stage: row (0..63)
    const int ak = (t & 3) * 16;    // A-stage: k offset
    const int sr = t >> 1;          // B-stage: column n (0..127)
    const int sk = (t & 1) * 32;    // B-stage: k half

    for (int k0 = 0; k0 < IN_DIM; k0 += KS) {
        {
            int gr = row0 + ar;
            if (gr > N_NODES - 1) gr = N_NODES - 1;
            const float* src = x + (size_t)gr * IN_DIM + k0 + ak;
            #pragma unroll
            for (int i = 0; i < 2; ++i) {
                float4 f0 = ((const float4*)src)[2 * i];
                float4 f1 = ((const float4*)src)[2 * i + 1];
                uint4 p;
                p.x = f2bf(f0.x) | ((unsigned)f2bf(f0.y) << 16);
                p.y = f2bf(f0.z) | ((unsigned)f2bf(f0.w) << 16);
                p.z = f2bf(f1.x) | ((unsigned)f2bf(f1.y) << 16);
                p.w = f2bf(f1.z) | ((unsigned)f2bf(f1.w) << 16);
                *(uint4*)&As[ar][ak + 8 * i] = p;
            }
            // B-stage: bf16 copy from pre-transposed W0T (L2-hot, 64 KB)
            const u16* wsrc = W0T + (size_t)sr * IN_DIM + k0 + sk;
            #pragma unroll
            for (int i = 0; i < 4; ++i)
                *(uint4*)&Bs[sr][sk + 8 * i] = ((const uint4*)wsrc)[i];
        }
        __syncthreads();
        #pragma unroll
        for (int kk = 0; kk < KS; kk += 32) {
            short8 a0 = *(const short8*)&As[w * 16 + sub][kk + quad * 8];
            #pragma unroll
            for (int ct = 0; ct < 8; ++ct) {
                short8 bb = *(const short8*)&Bs[ct * 16 + sub][kk + quad * 8];
                acc[ct] = __builtin_amdgcn_mfma_f32_16x16x32_bf16(a0, bb, acc[ct], 0, 0, 0);
            }
        }
        __syncthreads();
    }

    // epilogue: bias + relu + bf16 store; fused layer-1 scores
    float bias[8], w1c[8], w2c[8];
    #pragma unroll
    for (int ct = 0; ct < 8; ++ct) {
        const int col = ct * 16 + sub;
        bias[ct] = b0[col];
        w1c[ct] = aw1[col];
        w2c[ct] = aw1[HID + col];
    }
    #pragma unroll
    for (int reg = 0; reg < 4; ++reg) {
        const int gr = row0 + w * 16 + quad * 4 + reg;
        const bool ok = gr < N_NODES;
        float ps = 0.f, pd = 0.f;
        #pragma unroll
        for (int ct = 0; ct < 8; ++ct) {
            const float val = fmaxf(acc[ct][reg] + bias[ct], 0.f);
            if (ok) h[(size_t)gr * HID + ct * 16 + sub] = f2bf(val);
            ps += val * w1c[ct];
            pd += val * w2c[ct];
        }
        #pragma unroll
        for (int off = 1; off < 16; off <<= 1) {
            ps += __shfl_xor(ps, off);
            pd += __shfl_xor(pd, off);
        }
        if (sub == 0 && ok) { sa[gr] = ps; sb[gr] = pd; }
    }
}

// ---------- slot-CSR aggregation + eps-mix + relu + next-layer scores ----
// One QUARTER-WAVE (16 lanes) per node; lane sub owns channels 8*sub..8*sub+7.
// No LDS, no block barrier — waves retire independently. 8-edge batches,
// pipelined uint4 srcidx read, distributed tanh (lane sub&7 owns edge sub&7).
// (r4's 16-edge batches: VGPR blowup -> occupancy crash; do not retry.)
__global__ __launch_bounds__(256) void k_agg(const u16* __restrict__ hin,
                                             const float* __restrict__ sa,
                                             const float* __restrict__ sb,
                                             const float* __restrict__ attb,
                                             const float* __restrict__ epsp,
                                             const int* __restrict__ cnt,
                                             const u16* __restrict__ srcidx,
                                             u16* __restrict__ hout,
                                             const float* __restrict__ attw_next,
                                             float* __restrict__ sa_next,
                                             float* __restrict__ sb_next) {
    const int qid = threadIdx.x >> 4;   // 16 quarter-waves per block
    const int sub = threadIdx.x & 15;
    const int n = blockIdx.x * 16 + qid;
    if (n >= N_NODES) return;
    const float b = attb[0];
    const float sbn = sb[n];
    const int beg = n << 6;
    int deg = cnt[n];
    if (deg > SLOT) deg = SLOT;
    const int end = beg + deg;
    float acc[8];
    #pragma unroll
    for (int j = 0; j < 8; ++j) acc[j] = 0.f;

    int e = beg;
    uint4 svn;
    if (e + 8 <= end) svn = *(const uint4*)(srcidx + e);
    for (; e + 8 <= end; e += 8) {
        const uint4 sv = svn;
        if (e + 16 <= end) svn = *(const uint4*)(srcidx + e + 8);
        int s[8];
        s[0] = (int)(sv.x & 0xffffu); s[1] = (int)(sv.x >> 16);
        s[2] = (int)(sv.y & 0xffffu); s[3] = (int)(sv.y >> 16);
        s[4] = (int)(sv.z & 0xffffu); s[5] = (int)(sv.z >> 16);
        s[6] = (int)(sv.w & 0xffffu); s[7] = (int)(sv.w >> 16);
        uint4 v[8];
        #pragma unroll
        for (int i = 0; i < 8; ++i)
            v[i] = *(const uint4*)(hin + (size_t)s[i] * HID + sub * 8);
        // one tanh pass for all 8 edges (lane sub&7 owns edge sub&7)
        const float tt = tanhf(sa[s[sub & 7]] + sbn + b);
        float al[8];
        #pragma unroll
        for (int i = 0; i < 8; ++i) al[i] = __shfl(tt, i, 16);
        #pragma unroll
        for (int i = 0; i < 8; ++i) {
            float f[8];
            bf8_unpack(v[i], f);
            #pragma unroll
            for (int j = 0; j < 8; ++j) acc[j] += al[i] * f[j];
        }
    }
    const int rem = end - e;
    if (rem > 0) {
        const int sfirst = (int)srcidx[e];
        int s[8];
        #pragma unroll
        for (int i = 0; i < 8; ++i) s[i] = (i < rem) ? (int)srcidx[e + i] : sfirst;
        const float tt = ((sub & 7) < rem) ? tanhf(sa[s[sub & 7]] + sbn + b) : 0.f;
        float al[8];
        #pragma unroll
        for (int i = 0; i < 8; ++i) al[i] = __shfl(tt, i, 16);
        #pragma unroll
        for (int i = 0; i < 8; ++i) {
            if (i < rem) {
                const uint4 v = *(const uint4*)(hin + (size_t)s[i] * HID + sub * 8);
                float f[8];
                bf8_unpack(v, f);
                #pragma unroll
                for (int j = 0; j < 8; ++j) acc[j] += al[i] * f[j];
            }
        }
    }

    const float eps = epsp[0];
    const float om = 1.f - eps;
    const uint4 sv = *(const uint4*)(hin + (size_t)n * HID + sub * 8);
    float self[8], hv[8];
    bf8_unpack(sv, self);
    #pragma unroll
    for (int j = 0; j < 8; ++j)
        hv[j] = fmaxf(eps * self[j] + om * acc[j], 0.f);
    *(uint4*)(hout + (size_t)n * HID + sub * 8) = bf8_pack(hv);

    if (attw_next != nullptr) {
        float psum = 0.f, dsum = 0.f;
        #pragma unroll
        for (int j = 0; j < 8; ++j) {
            psum += hv[j] * attw_next[sub * 8 + j];
            dsum += hv[j] * attw_next[HID + sub * 8 + j];
        }
        #pragma unroll
        for (int off = 1; off < 16; off <<= 1) {
            psum += __shfl_xor(psum, off);
            dsum += __shfl_xor(dsum, off);
        }
        if (sub == 0) { sa_next[n] = psum; sb_next[n] = dsum; }
    }
}

// ---------- out = h2 @ Wc + bc via MFMA; 64 rows/block, LDS-staged h ----------
// (r1-measured form; r3/r4's LDS-free variant untested in isolation, revert.)
__global__ __launch_bounds__(256) void k_out_mfma(const u16* __restrict__ h,
                                                  const u16* __restrict__ Wct,
                                                  const float* __restrict__ bc,
                                                  float* __restrict__ out) {
    __shared__ u16 Hs[LR][HP];  // 17.4 KB
    const int t = threadIdx.x;
    const int lane = t & 63;
    const int w = t >> 6;
    const int sub = lane & 15;
    const int quad = lane >> 4;
    const int row0 = blockIdx.x * LR;

    // stage h: 64 rows x 128 ch bf16; thread t loads row t>>2, 32 ch (64 B)
    {
        const int hr = t >> 2;
        const int hc = (t & 3) * 32;
        int gr = row0 + hr;
        if (gr > N_NODES - 1) gr = N_NODES - 1;
        const u16* src = h + (size_t)gr * HID + hc;
        #pragma unroll
        for (int i = 0; i < 4; ++i)
            *(uint4*)&Hs[hr][hc + 8 * i] = ((const uint4*)src)[i];
    }
    __syncthreads();

    floatx4 acc[4];
    #pragma unroll
    for (int j = 0; j < 4; ++j) acc[j] = (floatx4){0.f, 0.f, 0.f, 0.f};

    #pragma unroll
    for (int ks = 0; ks < 4; ++ks) {
        const int ko = ks * 32 + quad * 8;
        short8 a = *(const short8*)&Hs[w * 16 + sub][ko];
        #pragma unroll
        for (int ct = 0; ct < 4; ++ct) {
            short8 bb = *(const short8*)(Wct + (ct * 16 + sub) * HID + ko);
            acc[ct] = __builtin_amdgcn_mfma_f32_16x16x32_bf16(a, bb, acc[ct], 0, 0, 0);
        }
    }

    #pragma unroll
    for (int ct = 0; ct < 4; ++ct) {
        const float bias = bc[ct * 16 + sub];
        #pragma unroll
        for (int reg = 0; reg < 4; ++reg) {
            const int gr = row0 + w * 16 + quad * 4 + reg;
            if (gr < N_NODES)
                out[(size_t)gr * OUT_DIM + ct * 16 + sub] = acc[ct][reg] + bias;
        }
    }
}

extern "C" void kernel_launch(void* const* d_in, const int* in_sizes, int n_in,
                              void* d_out, int out_size, void* d_ws, size_t ws_size,
                              hipStream_t stream) {
    const float* x   = (const float*)d_in[0];
    const int*   ei  = (const int*)d_in[1];
    const float* W0  = (const float*)d_in[2];
    const float* b0  = (const float*)d_in[3];
    const float* aw1 = (const float*)d_in[4];
    const float* ab1 = (const float*)d_in[5];
    const float* e1  = (const float*)d_in[6];
    const float* aw2 = (const float*)d_in[7];
    const float* ab2 = (const float*)d_in[8];
    const float* e2  = (const float*)d_in[9];
    const float* Wc  = (const float*)d_in[10];
    const float* bc  = (const float*)d_in[11];
    float* out = (float*)d_out;

    // workspace layout
    u16* hA  = (u16*)d_ws;                             // N*HID bf16
    u16* hB  = hA + (size_t)N_NODES * HID;             // N*HID bf16
    u16* W0T = hB + (size_t)N_NODES * HID;             // 256*128 bf16 (64 KB)
    u16* Wct = W0T + IN_DIM * HID;                     // 64*128 bf16 (16 KB)
    float* sa1 = (float*)(Wct + HID * OUT_DIM);        // N
    float* sb1 = sa1 + N_NODES;
    float* sa2 = sb1 + N_NODES;
    float* sb2 = sa2 + N_NODES;
    int* cnt    = (int*)(sb2 + N_NODES);               // N
    u16* srcidx = (u16*)(cnt + N_NODES);               // N*SLOT u16 (6.4 MB)

    k_pre<<<128, 256, 0, stream>>>(W0, Wc, W0T, Wct, cnt);
    k_front<<<NBUILD + NLIN, 256, 0, stream>>>(x, W0T, b0, aw1, hA, sa1, sb1,
                                               ei, cnt, srcidx);
    k_agg<<<(N_NODES + 15) / 16, 256, 0, stream>>>(hA, sa1, sb1, ab1, e1, cnt, srcidx,
                                                   hB, aw2, sa2, sb2);
    k_agg<<<(N_NODES + 15) / 16, 256, 0, stream>>>(hB, sa2, sb2, ab2, e2, cnt, srcidx,
                                                   hA, nullptr, nullptr, nullptr);
    k_out_mfma<<<NLIN, 256, 0, stream>>>(hA, Wct, bc, out);
}